// Round 5
// baseline (307.636 us; speedup 1.0000x reference)
//
#include <hip/hip_runtime.h>
#include <hip/hip_bf16.h>
#include <hip/hip_fp16.h>

// ---------------------------------------------------------------------------
// GCN link predictor, fp16 intermediates + MFMA GEMMs (fp32 accumulate):
//   h1 = X @ W1                                  (MFMA GEMM, fp32 A, UNSCALED)
//   z1 = relu(dinv[v]*(dinv[v]*h1[v] + sum dinv[s]*h1[s]) + b1)   (gather)
//   h2 = z1 @ W2                                 (MFMA GEMM, fp16 A, UNSCALED)
//   z2 = relu(dinv[v]*(dinv[v]*h2[v] + sum dinv[s]*h2[s]) + b2)   (gather)
//   out[e] = dot(z2[s], z2[d])
// CSR via slab bucket sort (bucket = dst>>8, CAP=5120 >> 15 sigma).
//
// R17: dinv DEFERRED from gemm epilogue into gather (per-edge dinv[s] is a
// broadcast 4B L2-hit + fmac; gather is miss-path-bound w/ VALUBusy 27% so
// it hides). This decouples gemm1 from the CSR chain -> csr || gemm1 FUSED
// in one dispatch (csr = 391 blocks ~19% occupancy idles the GPU otherwise).
// R16 lesson: gather is THROUGHPUT-bound on the L2-miss path (~3.1 TB/s):
// +28% in-flight (8-deep unroll) = 0 gain. 61 us/gather = structural floor
// for 25.6 MB random operand. 4-deep unroll (R0 proven) retained.
// R13 lesson: 32B column slices waste 4x on 128B lines — row-major only.
// R10-R12 lesson: unfused gather+gemm beats fused gather (80-85 vs 61+13).
// ---------------------------------------------------------------------------

typedef _Float16 half8 __attribute__((ext_vector_type(8)));
typedef float floatx4 __attribute__((ext_vector_type(4)));

#define BK_SHIFT 8
#define BSC_EDGES 2048  // edges per block in binning scatter
#define SLAB_CAP 5120   // per-bucket slab capacity (mean 4092, sd 64)
#define WPAD 136        // padded LDS row stride (halfs)

// ---- transpose + fp16-cast weights; blocks 0..3 also zero bfill
__global__ __launch_bounds__(128) void k_wprep(const float* __restrict__ W1,
                                               const float* __restrict__ W2,
                                               _Float16* __restrict__ WT1,
                                               _Float16* __restrict__ WT2,
                                               int* __restrict__ bfill) {
    int b = blockIdx.x;               // 0..255
    const float* W = (b < 128) ? W1 : W2;
    _Float16* WT = (b < 128) ? WT1 : WT2;
    int k = b & 127;
    int c = threadIdx.x;
    WT[c * 128 + k] = (_Float16)W[k * 128 + c];
    if (b < 4) bfill[b * 128 + c] = 0;   // 512 ints >= NBK
}

// ---- LDS-binned scatter of (src,dst) pairs into per-bucket slabs.
__global__ __launch_bounds__(256) void k_bscatter(const int* __restrict__ src,
                                                  const int* __restrict__ dst,
                                                  int* __restrict__ bfill,
                                                  int2* __restrict__ pairs,
                                                  int E, int nbk) {
    __shared__ int lcnt[1024];    // counts, then fill cursor (= lbase)
    __shared__ int delta[1024];   // slab_dest - lbase per bucket
    __shared__ int ssum[256];     // block-scan workspace
    __shared__ int2 stage[BSC_EDGES];
    int tid = threadIdx.x;
    int e0 = blockIdx.x * BSC_EDGES;
    int nloc = E - e0; if (nloc > BSC_EDGES) nloc = BSC_EDGES;

    for (int b = tid; b < nbk; b += 256) lcnt[b] = 0;
    __syncthreads();

    int d[BSC_EDGES / 256], s[BSC_EDGES / 256];
#pragma unroll
    for (int k = 0; k < BSC_EDGES / 256; ++k) {
        int e = e0 + k * 256 + tid;
        if (e < E) {
            d[k] = dst[e];
            s[k] = src[e];
            atomicAdd(&lcnt[d[k] >> BK_SHIFT], 1);
        } else d[k] = -1;
    }
    __syncthreads();

    const int gpb = (nbk + 255) >> 8;   // <=4 for nbk<=1024
    int c[4], mysum = 0;
    for (int t = 0; t < gpb; ++t) {
        int b = tid * gpb + t;
        c[t] = (b < nbk) ? lcnt[b] : 0;
        mysum += c[t];
    }
    ssum[tid] = mysum;
    __syncthreads();
    for (int off = 1; off < 256; off <<= 1) {
        int t = (tid >= off) ? ssum[tid - off] : 0;
        __syncthreads();
        ssum[tid] += t;
        __syncthreads();
    }
    int base = ssum[tid] - mysum;
    for (int t = 0; t < gpb; ++t) {
        int b = tid * gpb + t;
        if (b < nbk) {
            int g = c[t] ? atomicAdd(&bfill[b], c[t]) : 0;
            delta[b] = b * SLAB_CAP + g - base;   // slab dest - lbase
            lcnt[b] = base;                        // cursor starts at lbase
            base += c[t];
        }
    }
    __syncthreads();

#pragma unroll
    for (int k = 0; k < BSC_EDGES / 256; ++k) {
        if (d[k] >= 0) {
            int b = d[k] >> BK_SHIFT;
            int lp = atomicAdd(&lcnt[b], 1);
            int2 p; p.x = s[k]; p.y = d[k];
            stage[lp] = p;
        }
    }
    __syncthreads();

    for (int j = tid; j < nloc; j += 256) {
        int2 p = stage[j];
        pairs[delta[p.y >> BK_SHIFT] + j] = p;
    }
}

// ---------------------------------------------------------------------------
// FUSED: csr-build (blocks 0..nbk-1) || gemm1 (blocks nbk..nbk+gb-1).
// csr path: one block per bucket slab (256 nodes), 2 KB LDS.
// gemm path: unscaled (N x 128)@(128 x 128), 34.8 KB LDS (union'd).
// csr blocks dispatched first (they're the low-occupancy long pole).
// ---------------------------------------------------------------------------
template <typename AT>
__global__ __launch_bounds__(256) void k_csr_gemm(const int2* __restrict__ pairs,
                                                  const int* __restrict__ bfill,
                                                  int* __restrict__ row_start,
                                                  int* __restrict__ cnt,
                                                  float* __restrict__ dinv,
                                                  int* __restrict__ srcs,
                                                  const AT* __restrict__ X,
                                                  const _Float16* __restrict__ WT,
                                                  _Float16* __restrict__ G,
                                                  int n, int nbk) {
    __shared__ __align__(16) char smem[128 * WPAD * 2];   // 34816 B union
    int tid = threadIdx.x;

    if ((int)blockIdx.x < nbk) {
        // ---------------- CSR path (original k_csr body) ----------------
        int* lcnt = (int*)smem;        // [256]
        int* lpos = lcnt + 256;        // [256]
        int b = blockIdx.x;
        lcnt[tid] = 0;
        __syncthreads();
        int beg = b * SLAB_CAP, end = beg + bfill[b];
        for (int i = beg + tid; i < end; i += 256)
            atomicAdd(&lcnt[pairs[i].y & 255], 1);
        __syncthreads();
        int c = lcnt[tid];
        lpos[tid] = c;
        __syncthreads();
        for (int off = 1; off < 256; off <<= 1) {
            int t = (tid >= off) ? lpos[tid - off] : 0;
            __syncthreads();
            lpos[tid] += t;
            __syncthreads();
        }
        int rs = beg + lpos[tid] - c;   // row start (slab-relative, gaps ok)
        int v = (b << BK_SHIFT) + tid;
        if (v < n) {
            row_start[v] = rs;
            cnt[v] = c;
            dinv[v] = rsqrtf((float)c + 1.0f);
        }
        __syncthreads();
        lpos[tid] = rs;                 // reuse as fill cursor
        __syncthreads();
        for (int i = beg + tid; i < end; i += 256) {
            int2 p = pairs[i];
            int loc = atomicAdd(&lpos[p.y & 255], 1);
            srcs[loc] = p.x;
        }
        return;
    }

    // ---------------- GEMM path (unscaled epilogue) ----------------
    _Float16* Wl = (_Float16*)smem;    // [128 * WPAD]
    {
        const half8* w8 = (const half8*)WT;
#pragma unroll
        for (int i = 0; i < 8; ++i) {
            int idx = i * 256 + tid;
            int r = idx >> 4, cc = idx & 15;
            *(half8*)(Wl + r * WPAD + cc * 8) = w8[idx];
        }
    }
    __syncthreads();

    auto loadA = [](const AT* p) -> half8 {
        if constexpr (sizeof(AT) == 4) {
            const float4* f = (const float4*)p;
            float4 f0 = f[0], f1 = f[1];
            half8 a;
            a[0] = (_Float16)f0.x; a[1] = (_Float16)f0.y;
            a[2] = (_Float16)f0.z; a[3] = (_Float16)f0.w;
            a[4] = (_Float16)f1.x; a[5] = (_Float16)f1.y;
            a[6] = (_Float16)f1.z; a[7] = (_Float16)f1.w;
            return a;
        } else {
            return *(const half8*)p;
        }
    };

    int bid = blockIdx.x - nbk;
    int wave = tid >> 6, lane = tid & 63;
    int q = lane >> 4, ln = lane & 15;
    int m0 = bid * 128 + wave * 32;
    int mA0 = m0 + ln;      if (mA0 >= n) mA0 = n - 1;
    int mA1 = m0 + 16 + ln; if (mA1 >= n) mA1 = n - 1;
    const AT* xr0 = X + (size_t)mA0 * 128;
    const AT* xr1 = X + (size_t)mA1 * 128;

    floatx4 acc[2][8];
#pragma unroll
    for (int p = 0; p < 2; ++p)
#pragma unroll
        for (int t = 0; t < 8; ++t) acc[p][t] = (floatx4){0.f, 0.f, 0.f, 0.f};

#pragma unroll
    for (int kc = 0; kc < 128; kc += 32) {
        half8 a0 = loadA(xr0 + kc + q * 8);
        half8 a1 = loadA(xr1 + kc + q * 8);
#pragma unroll
        for (int t = 0; t < 8; ++t) {
            half8 b = *(const half8*)(Wl + (size_t)(t * 16 + ln) * WPAD + kc + q * 8);
            acc[0][t] = __builtin_amdgcn_mfma_f32_16x16x32_f16(a0, b, acc[0][t], 0, 0, 0);
            acc[1][t] = __builtin_amdgcn_mfma_f32_16x16x32_f16(a1, b, acc[1][t], 0, 0, 0);
        }
    }

#pragma unroll
    for (int p = 0; p < 2; ++p) {
#pragma unroll
        for (int r = 0; r < 4; ++r) {
            int row = m0 + p * 16 + q * 4 + r;
            if (row < n) {
                _Float16* grow = G + (size_t)row * 128 + ln;
#pragma unroll
                for (int t = 0; t < 8; ++t)
                    grow[t * 16] = (_Float16)acc[p][t][r];
            }
        }
    }
}

// ---------------------------------------------------------------------------
// Standalone unscaled GEMM (layer 2). Same body as gemm path above.
// ---------------------------------------------------------------------------
template <typename AT>
__global__ __launch_bounds__(256) void k_gemm_mfma(const AT* __restrict__ X,
                                                   const _Float16* __restrict__ WT,
                                                   _Float16* __restrict__ G, int n) {
    __shared__ _Float16 Wl[128 * WPAD];
    int tid = threadIdx.x;
    {
        const half8* w8 = (const half8*)WT;
#pragma unroll
        for (int i = 0; i < 8; ++i) {
            int idx = i * 256 + tid;
            int r = idx >> 4, cc = idx & 15;
            *(half8*)(Wl + r * WPAD + cc * 8) = w8[idx];
        }
    }
    __syncthreads();

    auto loadA = [](const AT* p) -> half8 {
        if constexpr (sizeof(AT) == 4) {
            const float4* f = (const float4*)p;
            float4 f0 = f[0], f1 = f[1];
            half8 a;
            a[0] = (_Float16)f0.x; a[1] = (_Float16)f0.y;
            a[2] = (_Float16)f0.z; a[3] = (_Float16)f0.w;
            a[4] = (_Float16)f1.x; a[5] = (_Float16)f1.y;
            a[6] = (_Float16)f1.z; a[7] = (_Float16)f1.w;
            return a;
        } else {
            return *(const half8*)p;
        }
    };

    int wave = tid >> 6, lane = tid & 63;
    int q = lane >> 4, ln = lane & 15;
    int m0 = blockIdx.x * 128 + wave * 32;
    int mA0 = m0 + ln;      if (mA0 >= n) mA0 = n - 1;
    int mA1 = m0 + 16 + ln; if (mA1 >= n) mA1 = n - 1;
    const AT* xr0 = X + (size_t)mA0 * 128;
    const AT* xr1 = X + (size_t)mA1 * 128;

    floatx4 acc[2][8];
#pragma unroll
    for (int p = 0; p < 2; ++p)
#pragma unroll
        for (int t = 0; t < 8; ++t) acc[p][t] = (floatx4){0.f, 0.f, 0.f, 0.f};

#pragma unroll
    for (int kc = 0; kc < 128; kc += 32) {
        half8 a0 = loadA(xr0 + kc + q * 8);
        half8 a1 = loadA(xr1 + kc + q * 8);
#pragma unroll
        for (int t = 0; t < 8; ++t) {
            half8 b = *(const half8*)(Wl + (size_t)(t * 16 + ln) * WPAD + kc + q * 8);
            acc[0][t] = __builtin_amdgcn_mfma_f32_16x16x32_f16(a0, b, acc[0][t], 0, 0, 0);
            acc[1][t] = __builtin_amdgcn_mfma_f32_16x16x32_f16(a1, b, acc[1][t], 0, 0, 0);
        }
    }

#pragma unroll
    for (int p = 0; p < 2; ++p) {
#pragma unroll
        for (int r = 0; r < 4; ++r) {
            int row = m0 + p * 16 + q * 4 + r;
            if (row < n) {
                _Float16* grow = G + (size_t)row * 128 + ln;
#pragma unroll
                for (int t = 0; t < 8; ++t)
                    grow[t * 16] = (_Float16)acc[p][t][r];
            }
        }
    }
}

// ---------------------------------------------------------------------------
// Gather + bias + relu -> Z (fp16). 16 lanes/node, half8 rows, fp32 accum.
// R17: per-edge dinv[s] scaling (deferred from gemm). 4-deep unroll (R0
// proven shape; R16 showed deeper unroll is neutral — miss-path bound).
// ---------------------------------------------------------------------------
__global__ __launch_bounds__(256) void k_gather_relu(const _Float16* __restrict__ G,
                                                     const int* __restrict__ srcs,
                                                     const int* __restrict__ row_start,
                                                     const int* __restrict__ cnt,
                                                     const float* __restrict__ dinv,
                                                     const float* __restrict__ bias,
                                                     _Float16* __restrict__ Z, int n) {
    int v = blockIdx.x * 16 + (threadIdx.x >> 4);
    int lane = threadIdx.x & 15;
    if (v >= n) return;
    const half8* G8 = (const half8*)G;

    float dv = dinv[v];
    half8 self = G8[(size_t)v * 16 + lane];
    float acc[8], acc2[8];
#pragma unroll
    for (int j = 0; j < 8; ++j) { acc[j] = dv * (float)self[j]; acc2[j] = 0.f; }

    int beg = row_start[v], deg = cnt[v];
    int e = 0;
    for (; e + 3 < deg; e += 4) {
        int s0 = srcs[beg + e];
        int s1 = srcs[beg + e + 1];
        int s2 = srcs[beg + e + 2];
        int s3 = srcs[beg + e + 3];
        float d0 = dinv[s0];
        float d1 = dinv[s1];
        float d2 = dinv[s2];
        float d3 = dinv[s3];
        half8 t0 = G8[(size_t)s0 * 16 + lane];
        half8 t1 = G8[(size_t)s1 * 16 + lane];
        half8 t2 = G8[(size_t)s2 * 16 + lane];
        half8 t3 = G8[(size_t)s3 * 16 + lane];
#pragma unroll
        for (int j = 0; j < 8; ++j) {
            acc[j]  += d0 * (float)t0[j] + d1 * (float)t1[j];
            acc2[j] += d2 * (float)t2[j] + d3 * (float)t3[j];
        }
    }
    for (; e < deg; ++e) {
        int s0 = srcs[beg + e];
        float d0 = dinv[s0];
        half8 t0 = G8[(size_t)s0 * 16 + lane];
#pragma unroll
        for (int j = 0; j < 8; ++j) acc[j] += d0 * (float)t0[j];
    }

    const float4* b4 = (const float4*)bias;
    float4 bb0 = b4[lane * 2], bb1 = b4[lane * 2 + 1];
    float bf[8] = {bb0.x, bb0.y, bb0.z, bb0.w, bb1.x, bb1.y, bb1.z, bb1.w};
    half8 zo;
#pragma unroll
    for (int j = 0; j < 8; ++j) {
        float z = dv * (acc[j] + acc2[j]) + bf[j];
        zo[j] = (_Float16)fmaxf(z, 0.f);
    }
    ((half8*)Z)[(size_t)v * 16 + lane] = zo;
}

// ---------------------------------------------------------------------------
// Decode: out[e] = dot(Z[s_e], Z[d_e]) over 128 dims (fp16 rows, fp32 accum).
// ---------------------------------------------------------------------------
__global__ __launch_bounds__(256) void k_decode(const _Float16* __restrict__ Z,
                                                const int* __restrict__ eli,
                                                float* __restrict__ out, int el) {
    int sub = threadIdx.x >> 4, lane = threadIdx.x & 15;
    int e = blockIdx.x * 16 + sub;
    if (e >= el) return;
    int s = eli[e], d = eli[el + e];
    const half8* Z8 = (const half8*)Z;
    half8 a = Z8[(size_t)s * 16 + lane];
    half8 b = Z8[(size_t)d * 16 + lane];
    float dot = 0.f;
#pragma unroll
    for (int j = 0; j < 8; ++j) dot += (float)a[j] * (float)b[j];
#pragma unroll
    for (int off = 8; off; off >>= 1) dot += __shfl_down(dot, off, 16);
    if (lane == 0) out[e] = dot;
}

extern "C" void kernel_launch(void* const* d_in, const int* in_sizes, int n_in,
                              void* d_out, int out_size, void* d_ws, size_t ws_size,
                              hipStream_t stream) {
    const float* x  = (const float*)d_in[0];
    const int*  ei  = (const int*)d_in[1];
    const int*  eli = (const int*)d_in[2];
    const float* W1 = (const float*)d_in[3];
    const float* b1 = (const float*)d_in[4];
    const float* W2 = (const float*)d_in[5];
    const float* b2 = (const float*)d_in[6];
    float* out = (float*)d_out;

    const int N  = in_sizes[0] / 128;
    const int E  = in_sizes[1] / 2;
    const int EL = in_sizes[2] / 2;
    const int* src = ei;
    const int* dst = ei + E;
    const int NBK = (N + 255) >> BK_SHIFT;   // 391 for N=100000
    const int GB  = (N + 127) / 128;         // gemm blocks = 782

    char* ws = (char*)d_ws;
    size_t off = 0;
    auto alloc = [&](size_t bytes) -> void* {
        void* p = ws + off;
        off += bytes;
        off = (off + 255) & ~(size_t)255;
        return p;
    };
    int*       cnt       = (int*)alloc((size_t)N * 4);
    int*       row_start = (int*)alloc((size_t)N * 4);
    float*     dinv      = (float*)alloc((size_t)N * 4);
    int*       bfill     = (int*)alloc(4096);
    _Float16*  WT1       = (_Float16*)alloc(128 * 128 * 2);
    _Float16*  WT2       = (_Float16*)alloc(128 * 128 * 2);
    int*       srcs      = (int*)alloc((size_t)NBK * SLAB_CAP * 4);
    int2*      pairs     = (int2*)alloc((size_t)NBK * SLAB_CAP * 8);
    _Float16*  buf0      = (_Float16*)alloc((size_t)N * 128 * 2);  // h1 -> h2
    _Float16*  buf1      = (_Float16*)alloc((size_t)N * 128 * 2);  // z1 -> z2

    // weight prep + bfill zero (one launch)
    k_wprep<<<256, 128, 0, stream>>>(W1, W2, WT1, WT2, bfill);

    // CSR build: slab bucket sort (no count/scan pre-pass)
    k_bscatter<<<(E + BSC_EDGES - 1) / BSC_EDGES, 256, 0, stream>>>(src, dst, bfill, pairs, E, NBK);

    // fused: csr (391 blocks) || gemm1 h1 = x@W1 -> buf0 (782 blocks)
    k_csr_gemm<float><<<NBK + GB, 256, 0, stream>>>(pairs, bfill, row_start, cnt, dinv,
                                                    srcs, x, WT1, buf0, N, NBK);

    // z1 = relu(dinv*(dinv*h1[v] + sum dinv[s]*h1[s]) + b1) -> buf1
    k_gather_relu<<<(N + 15) / 16, 256, 0, stream>>>(buf0, srcs, row_start, cnt, dinv, b1, buf1, N);
    // layer 2: h2 = z1@W2 -> buf0 ; z2 -> buf1
    k_gemm_mfma<_Float16><<<GB, 256, 0, stream>>>(buf1, WT2, buf0, N);
    k_gather_relu<<<(N + 15) / 16, 256, 0, stream>>>(buf0, srcs, row_start, cnt, dinv, b2, buf1, N);
    // decode
    k_decode<<<(EL + 15) / 16, 256, 0, stream>>>(buf1, eli, out, EL);
}

// Round 6
// 277.908 us; speedup vs baseline: 1.1070x; 1.1070x over previous
//
#include <hip/hip_runtime.h>
#include <hip/hip_bf16.h>
#include <hip/hip_fp16.h>

// ---------------------------------------------------------------------------
// GCN link predictor, fp16 intermediates + MFMA GEMMs (fp32 accumulate):
//   h1 = X @ W1                                  (MFMA GEMM, fp32 A, UNSCALED)
//   z1 = relu(dinv[v]*(dinv[v]*h1[v] + sum dinv[s]*h1[s]) + b1)   (gather)
//   h2 = z1 @ W2                                 (MFMA GEMM, fp16 A, UNSCALED)
//   z2 = relu(dinv[v]*(dinv[v]*h2[v] + sum dinv[s]*h2[s]) + b2)   (gather)
//   out[e] = dot(z2[s], z2[d])
//
// R18: PRIVATIZED BINNING replaces slab bucket-sort scatter.
//   - k_bin: each block bucket-sorts its 2048 edges in LDS, writes them
//     PACKED ((s<<8)|(d&255), 1 int/edge) to a PRIVATE contiguous region
//     bins[blk*2048..] (coalesced, no global atomics, no cross-XCD line
//     sharing) + per-block bucket offsets P[blk][nbk+1] (coalesced row).
//     Old bscatter wrote int2 pairs into shared slabs: ~42B runs from
//     different blocks/XCDs sharing 128B lines -> sector-masked write
//     inefficiency + 2 global-atomic passes. bfill/pairs DELETED.
//   - k_csr: gathers bucket b's edges from 782 private segments (P is
//     1.2MB -> L2-resident) into LDS stage, then the proven counting
//     sort (count/scan/scatter) from LDS. Scattered READS, no RMW.
//   - wprep folded into k_bin tail blocks; csr stays fused w/ gemm1.
//   7 -> 6 dispatches.
// R17: dinv deferred into gather (gemm epilogues unscaled) - kept.
// R16 lesson: gather is THROUGHPUT-bound on L2-miss path; 61-62 us floor.
// R13 lesson: 32B column slices waste 4x on 128B lines - row-major only.
// R10-R12 lesson: unfused gather+gemm beats fused gather (80-85 vs 61+13).
// ---------------------------------------------------------------------------

typedef _Float16 half8 __attribute__((ext_vector_type(8)));
typedef float floatx4 __attribute__((ext_vector_type(4)));

#define BK_SHIFT 8
#define BSC_EDGES 2048  // edges per bin block
#define SLAB_CAP 5120   // per-bucket capacity (mean 4092, sd 64, +16 sigma)
#define WPAD 136        // padded LDS row stride (halfs)

// ---------------------------------------------------------------------------
// k_bin: private bucket-sort of 2048 edges/block + weight-prep tail blocks.
// blocks [0, nbin): binning. blocks [nbin, nbin+256): wprep (128 lanes).
// ---------------------------------------------------------------------------
__global__ __launch_bounds__(256) void k_bin(const int* __restrict__ src,
                                             const int* __restrict__ dst,
                                             int* __restrict__ bins,
                                             int* __restrict__ P,
                                             int E, int nbk, int nbin,
                                             const float* __restrict__ W1,
                                             const float* __restrict__ W2,
                                             _Float16* __restrict__ WT1,
                                             _Float16* __restrict__ WT2) {
    int tid = threadIdx.x;
    if ((int)blockIdx.x >= nbin) {
        // ---- weight prep: transpose + fp16 cast (2 x 128x128) ----
        int b2 = blockIdx.x - nbin;          // 0..255
        if (tid < 128) {
            const float* W = (b2 < 128) ? W1 : W2;
            _Float16* WT = (b2 < 128) ? WT1 : WT2;
            int k = b2 & 127;
            WT[tid * 128 + k] = (_Float16)W[k * 128 + tid];
        }
        return;
    }

    __shared__ int lcnt[1024];    // counts -> fill cursor
    __shared__ int delta[1024];   // saved bucket base (intra-block offset)
    __shared__ int ssum[256];     // block-scan workspace
    __shared__ int stage[BSC_EDGES];
    int e0 = blockIdx.x * BSC_EDGES;
    int nloc = E - e0; if (nloc > BSC_EDGES) nloc = BSC_EDGES;

    for (int b = tid; b < nbk; b += 256) lcnt[b] = 0;
    __syncthreads();

    int d[BSC_EDGES / 256], s[BSC_EDGES / 256];
#pragma unroll
    for (int k = 0; k < BSC_EDGES / 256; ++k) {
        int e = e0 + k * 256 + tid;
        if (e < E) {
            d[k] = dst[e];
            s[k] = src[e];
            atomicAdd(&lcnt[d[k] >> BK_SHIFT], 1);
        } else d[k] = -1;
    }
    __syncthreads();

    const int gpb = (nbk + 255) >> 8;   // 2 for nbk=391
    int c[4], mysum = 0;
    for (int t = 0; t < gpb; ++t) {
        int b = tid * gpb + t;
        c[t] = (b < nbk) ? lcnt[b] : 0;
        mysum += c[t];
    }
    ssum[tid] = mysum;
    __syncthreads();
    for (int off = 1; off < 256; off <<= 1) {
        int t = (tid >= off) ? ssum[tid - off] : 0;
        __syncthreads();
        ssum[tid] += t;
        __syncthreads();
    }
    int base = ssum[tid] - mysum;
    for (int t = 0; t < gpb; ++t) {
        int b = tid * gpb + t;
        if (b < nbk) {
            delta[b] = base;      // bucket start (intra-block)
            lcnt[b] = base;       // fill cursor
            base += c[t];
        }
    }
    __syncthreads();

#pragma unroll
    for (int k = 0; k < BSC_EDGES / 256; ++k) {
        if (d[k] >= 0) {
            int b = d[k] >> BK_SHIFT;
            int lp = atomicAdd(&lcnt[b], 1);
            stage[lp] = (s[k] << 8) | (d[k] & 255);   // packed edge
        }
    }
    __syncthreads();

    // private contiguous writes: fully coalesced, no sharing
    int* bb = bins + (size_t)blockIdx.x * BSC_EDGES;
    for (int j = tid; j < nloc; j += 256) bb[j] = stage[j];
    // bucket-offset row (nbk+1 ints, contiguous)
    int prow = nbk + 1;
    int* pp = P + (size_t)blockIdx.x * prow;
    for (int b = tid; b <= nbk; b += 256)
        pp[b] = (b < nbk) ? delta[b] : nloc;   // sentinel = nloc
}

// ---------------------------------------------------------------------------
// FUSED: csr-build (blocks 0..nbk-1) || gemm1 (blocks nbk..nbk+gb-1).
// csr path: gather bucket b's edges from nbin private segments into LDS
// (P L2-resident), then counting sort: count/scan/scatter -> srcs slab.
// gemm path: unscaled (N x 128)@(128 x 128), 34.8 KB LDS (union'd).
// ---------------------------------------------------------------------------
template <typename AT>
__global__ __launch_bounds__(256) void k_csr_gemm(const int* __restrict__ bins,
                                                  const int* __restrict__ P,
                                                  int* __restrict__ row_start,
                                                  int* __restrict__ cnt,
                                                  float* __restrict__ dinv,
                                                  int* __restrict__ srcs,
                                                  const AT* __restrict__ X,
                                                  const _Float16* __restrict__ WT,
                                                  _Float16* __restrict__ G,
                                                  int n, int nbk, int nbin) {
    __shared__ __align__(16) char smem[128 * WPAD * 2];   // 34816 B union
    int tid = threadIdx.x;

    if ((int)blockIdx.x < nbk) {
        // ---------------- CSR path ----------------
        int* stage = (int*)smem;                    // [SLAB_CAP] 20480 B
        int* lcnt  = (int*)(smem + 20480);          // [256]
        int* lpos  = (int*)(smem + 21504);          // [256]
        int* curs  = (int*)(smem + 22528);          // [1]
        int b = blockIdx.x;
        int prow = nbk + 1;
        if (tid == 0) *curs = 0;
        __syncthreads();
        // phase A: pull my bucket's edges from private segments into LDS
        for (int seg = tid; seg < nbin; seg += 256) {
            const int* pp = P + (size_t)seg * prow + b;
            int p0 = pp[0], p1 = pp[1];
            int len = p1 - p0;
            if (len > 0) {
                int off = atomicAdd(curs, len);
                const int* sp = bins + (size_t)seg * BSC_EDGES + p0;
                for (int i = 0; i < len; ++i) stage[off + i] = sp[i];
            }
        }
        __syncthreads();
        int tot = *curs;
        // phase B: counting sort over 256 dst slots
        lcnt[tid] = 0;
        __syncthreads();
        for (int i = tid; i < tot; i += 256)
            atomicAdd(&lcnt[stage[i] & 255], 1);
        __syncthreads();
        int c = lcnt[tid];
        lpos[tid] = c;
        __syncthreads();
        for (int off = 1; off < 256; off <<= 1) {
            int t = (tid >= off) ? lpos[tid - off] : 0;
            __syncthreads();
            lpos[tid] += t;
            __syncthreads();
        }
        int rs = b * SLAB_CAP + lpos[tid] - c;   // row start in srcs slab
        int v = (b << BK_SHIFT) + tid;
        if (v < n) {
            row_start[v] = rs;
            cnt[v] = c;
            dinv[v] = rsqrtf((float)c + 1.0f);
        }
        __syncthreads();
        lpos[tid] = rs;                 // reuse as fill cursor
        __syncthreads();
        for (int i = tid; i < tot; i += 256) {
            int p = stage[i];
            int loc = atomicAdd(&lpos[p & 255], 1);
            srcs[loc] = p >> 8;
        }
        return;
    }

    // ---------------- GEMM path (unscaled epilogue) ----------------
    _Float16* Wl = (_Float16*)smem;    // [128 * WPAD]
    {
        const half8* w8 = (const half8*)WT;
#pragma unroll
        for (int i = 0; i < 8; ++i) {
            int idx = i * 256 + tid;
            int r = idx >> 4, cc = idx & 15;
            *(half8*)(Wl + r * WPAD + cc * 8) = w8[idx];
        }
    }
    __syncthreads();

    auto loadA = [](const AT* p) -> half8 {
        if constexpr (sizeof(AT) == 4) {
            const float4* f = (const float4*)p;
            float4 f0 = f[0], f1 = f[1];
            half8 a;
            a[0] = (_Float16)f0.x; a[1] = (_Float16)f0.y;
            a[2] = (_Float16)f0.z; a[3] = (_Float16)f0.w;
            a[4] = (_Float16)f1.x; a[5] = (_Float16)f1.y;
            a[6] = (_Float16)f1.z; a[7] = (_Float16)f1.w;
            return a;
        } else {
            return *(const half8*)p;
        }
    };

    int bid = blockIdx.x - nbk;
    int wave = tid >> 6, lane = tid & 63;
    int q = lane >> 4, ln = lane & 15;
    int m0 = bid * 128 + wave * 32;
    int mA0 = m0 + ln;      if (mA0 >= n) mA0 = n - 1;
    int mA1 = m0 + 16 + ln; if (mA1 >= n) mA1 = n - 1;
    const AT* xr0 = X + (size_t)mA0 * 128;
    const AT* xr1 = X + (size_t)mA1 * 128;

    floatx4 acc[2][8];
#pragma unroll
    for (int p = 0; p < 2; ++p)
#pragma unroll
        for (int t = 0; t < 8; ++t) acc[p][t] = (floatx4){0.f, 0.f, 0.f, 0.f};

#pragma unroll
    for (int kc = 0; kc < 128; kc += 32) {
        half8 a0 = loadA(xr0 + kc + q * 8);
        half8 a1 = loadA(xr1 + kc + q * 8);
#pragma unroll
        for (int t = 0; t < 8; ++t) {
            half8 b = *(const half8*)(Wl + (size_t)(t * 16 + ln) * WPAD + kc + q * 8);
            acc[0][t] = __builtin_amdgcn_mfma_f32_16x16x32_f16(a0, b, acc[0][t], 0, 0, 0);
            acc[1][t] = __builtin_amdgcn_mfma_f32_16x16x32_f16(a1, b, acc[1][t], 0, 0, 0);
        }
    }

#pragma unroll
    for (int p = 0; p < 2; ++p) {
#pragma unroll
        for (int r = 0; r < 4; ++r) {
            int row = m0 + p * 16 + q * 4 + r;
            if (row < n) {
                _Float16* grow = G + (size_t)row * 128 + ln;
#pragma unroll
                for (int t = 0; t < 8; ++t)
                    grow[t * 16] = (_Float16)acc[p][t][r];
            }
        }
    }
}

// ---------------------------------------------------------------------------
// Standalone unscaled GEMM (layer 2).
// ---------------------------------------------------------------------------
template <typename AT>
__global__ __launch_bounds__(256) void k_gemm_mfma(const AT* __restrict__ X,
                                                   const _Float16* __restrict__ WT,
                                                   _Float16* __restrict__ G, int n) {
    __shared__ _Float16 Wl[128 * WPAD];
    int tid = threadIdx.x;
    {
        const half8* w8 = (const half8*)WT;
#pragma unroll
        for (int i = 0; i < 8; ++i) {
            int idx = i * 256 + tid;
            int r = idx >> 4, cc = idx & 15;
            *(half8*)(Wl + r * WPAD + cc * 8) = w8[idx];
        }
    }
    __syncthreads();

    auto loadA = [](const AT* p) -> half8 {
        if constexpr (sizeof(AT) == 4) {
            const float4* f = (const float4*)p;
            float4 f0 = f[0], f1 = f[1];
            half8 a;
            a[0] = (_Float16)f0.x; a[1] = (_Float16)f0.y;
            a[2] = (_Float16)f0.z; a[3] = (_Float16)f0.w;
            a[4] = (_Float16)f1.x; a[5] = (_Float16)f1.y;
            a[6] = (_Float16)f1.z; a[7] = (_Float16)f1.w;
            return a;
        } else {
            return *(const half8*)p;
        }
    };

    int wave = tid >> 6, lane = tid & 63;
    int q = lane >> 4, ln = lane & 15;
    int m0 = blockIdx.x * 128 + wave * 32;
    int mA0 = m0 + ln;      if (mA0 >= n) mA0 = n - 1;
    int mA1 = m0 + 16 + ln; if (mA1 >= n) mA1 = n - 1;
    const AT* xr0 = X + (size_t)mA0 * 128;
    const AT* xr1 = X + (size_t)mA1 * 128;

    floatx4 acc[2][8];
#pragma unroll
    for (int p = 0; p < 2; ++p)
#pragma unroll
        for (int t = 0; t < 8; ++t) acc[p][t] = (floatx4){0.f, 0.f, 0.f, 0.f};

#pragma unroll
    for (int kc = 0; kc < 128; kc += 32) {
        half8 a0 = loadA(xr0 + kc + q * 8);
        half8 a1 = loadA(xr1 + kc + q * 8);
#pragma unroll
        for (int t = 0; t < 8; ++t) {
            half8 b = *(const half8*)(Wl + (size_t)(t * 16 + ln) * WPAD + kc + q * 8);
            acc[0][t] = __builtin_amdgcn_mfma_f32_16x16x32_f16(a0, b, acc[0][t], 0, 0, 0);
            acc[1][t] = __builtin_amdgcn_mfma_f32_16x16x32_f16(a1, b, acc[1][t], 0, 0, 0);
        }
    }

#pragma unroll
    for (int p = 0; p < 2; ++p) {
#pragma unroll
        for (int r = 0; r < 4; ++r) {
            int row = m0 + p * 16 + q * 4 + r;
            if (row < n) {
                _Float16* grow = G + (size_t)row * 128 + ln;
#pragma unroll
                for (int t = 0; t < 8; ++t)
                    grow[t * 16] = (_Float16)acc[p][t][r];
            }
        }
    }
}

// ---------------------------------------------------------------------------
// Gather + bias + relu -> Z (fp16). 16 lanes/node, half8 rows, fp32 accum.
// Per-edge dinv[s] scaling (deferred from gemm). 4-deep unroll (R0 proven;
// R16: deeper unroll neutral — miss-path throughput bound).
// ---------------------------------------------------------------------------
__global__ __launch_bounds__(256) void k_gather_relu(const _Float16* __restrict__ G,
                                                     const int* __restrict__ srcs,
                                                     const int* __restrict__ row_start,
                                                     const int* __restrict__ cnt,
                                                     const float* __restrict__ dinv,
                                                     const float* __restrict__ bias,
                                                     _Float16* __restrict__ Z, int n) {
    int v = blockIdx.x * 16 + (threadIdx.x >> 4);
    int lane = threadIdx.x & 15;
    if (v >= n) return;
    const half8* G8 = (const half8*)G;

    float dv = dinv[v];
    half8 self = G8[(size_t)v * 16 + lane];
    float acc[8], acc2[8];
#pragma unroll
    for (int j = 0; j < 8; ++j) { acc[j] = dv * (float)self[j]; acc2[j] = 0.f; }

    int beg = row_start[v], deg = cnt[v];
    int e = 0;
    for (; e + 3 < deg; e += 4) {
        int s0 = srcs[beg + e];
        int s1 = srcs[beg + e + 1];
        int s2 = srcs[beg + e + 2];
        int s3 = srcs[beg + e + 3];
        float d0 = dinv[s0];
        float d1 = dinv[s1];
        float d2 = dinv[s2];
        float d3 = dinv[s3];
        half8 t0 = G8[(size_t)s0 * 16 + lane];
        half8 t1 = G8[(size_t)s1 * 16 + lane];
        half8 t2 = G8[(size_t)s2 * 16 + lane];
        half8 t3 = G8[(size_t)s3 * 16 + lane];
#pragma unroll
        for (int j = 0; j < 8; ++j) {
            acc[j]  += d0 * (float)t0[j] + d1 * (float)t1[j];
            acc2[j] += d2 * (float)t2[j] + d3 * (float)t3[j];
        }
    }
    for (; e < deg; ++e) {
        int s0 = srcs[beg + e];
        float d0 = dinv[s0];
        half8 t0 = G8[(size_t)s0 * 16 + lane];
#pragma unroll
        for (int j = 0; j < 8; ++j) acc[j] += d0 * (float)t0[j];
    }

    const float4* b4 = (const float4*)bias;
    float4 bb0 = b4[lane * 2], bb1 = b4[lane * 2 + 1];
    float bf[8] = {bb0.x, bb0.y, bb0.z, bb0.w, bb1.x, bb1.y, bb1.z, bb1.w};
    half8 zo;
#pragma unroll
    for (int j = 0; j < 8; ++j) {
        float z = dv * (acc[j] + acc2[j]) + bf[j];
        zo[j] = (_Float16)fmaxf(z, 0.f);
    }
    ((half8*)Z)[(size_t)v * 16 + lane] = zo;
}

// ---------------------------------------------------------------------------
// Decode: out[e] = dot(Z[s_e], Z[d_e]) over 128 dims (fp16 rows, fp32 accum).
// ---------------------------------------------------------------------------
__global__ __launch_bounds__(256) void k_decode(const _Float16* __restrict__ Z,
                                                const int* __restrict__ eli,
                                                float* __restrict__ out, int el) {
    int sub = threadIdx.x >> 4, lane = threadIdx.x & 15;
    int e = blockIdx.x * 16 + sub;
    if (e >= el) return;
    int s = eli[e], d = eli[el + e];
    const half8* Z8 = (const half8*)Z;
    half8 a = Z8[(size_t)s * 16 + lane];
    half8 b = Z8[(size_t)d * 16 + lane];
    float dot = 0.f;
#pragma unroll
    for (int j = 0; j < 8; ++j) dot += (float)a[j] * (float)b[j];
#pragma unroll
    for (int off = 8; off; off >>= 1) dot += __shfl_down(dot, off, 16);
    if (lane == 0) out[e] = dot;
}

extern "C" void kernel_launch(void* const* d_in, const int* in_sizes, int n_in,
                              void* d_out, int out_size, void* d_ws, size_t ws_size,
                              hipStream_t stream) {
    const float* x  = (const float*)d_in[0];
    const int*  ei  = (const int*)d_in[1];
    const int*  eli = (const int*)d_in[2];
    const float* W1 = (const float*)d_in[3];
    const float* b1 = (const float*)d_in[4];
    const float* W2 = (const float*)d_in[5];
    const float* b2 = (const float*)d_in[6];
    float* out = (float*)d_out;

    const int N  = in_sizes[0] / 128;
    const int E  = in_sizes[1] / 2;
    const int EL = in_sizes[2] / 2;
    const int* src = ei;
    const int* dst = ei + E;
    const int NBK  = (N + 255) >> BK_SHIFT;                 // 391
    const int NBIN = (E + BSC_EDGES - 1) / BSC_EDGES;       // 782
    const int GB   = (N + 127) / 128;                       // 782

    char* ws = (char*)d_ws;
    size_t off = 0;
    auto alloc = [&](size_t bytes) -> void* {
        void* p = ws + off;
        off += bytes;
        off = (off + 255) & ~(size_t)255;
        return p;
    };
    int*       cnt       = (int*)alloc((size_t)N * 4);
    int*       row_start = (int*)alloc((size_t)N * 4);
    float*     dinv      = (float*)alloc((size_t)N * 4);
    _Float16*  WT1       = (_Float16*)alloc(128 * 128 * 2);
    _Float16*  WT2       = (_Float16*)alloc(128 * 128 * 2);
    int*       srcs      = (int*)alloc((size_t)NBK * SLAB_CAP * 4);
    int*       bins      = (int*)alloc((size_t)NBIN * BSC_EDGES * 4);
    int*       P         = (int*)alloc((size_t)NBIN * (NBK + 1) * 4);
    _Float16*  buf0      = (_Float16*)alloc((size_t)N * 128 * 2);  // h1 -> h2
    _Float16*  buf1      = (_Float16*)alloc((size_t)N * 128 * 2);  // z1 -> z2

    // private binning (+ weight prep in tail blocks)
    k_bin<<<NBIN + 256, 256, 0, stream>>>(src, dst, bins, P, E, NBK, NBIN,
                                          W1, W2, WT1, WT2);

    // fused: csr (391 blocks) || gemm1 h1 = x@W1 -> buf0 (782 blocks)
    k_csr_gemm<float><<<NBK + GB, 256, 0, stream>>>(bins, P, row_start, cnt, dinv,
                                                    srcs, x, WT1, buf0, N, NBK, NBIN);

    // z1 = relu(dinv*(dinv*h1[v] + sum dinv[s]*h1[s]) + b1) -> buf1
    k_gather_relu<<<(N + 15) / 16, 256, 0, stream>>>(buf0, srcs, row_start, cnt, dinv, b1, buf1, N);
    // layer 2: h2 = z1@W2 -> buf0 ; z2 -> buf1
    k_gemm_mfma<_Float16><<<GB, 256, 0, stream>>>(buf1, WT2, buf0, N);
    k_gather_relu<<<(N + 15) / 16, 256, 0, stream>>>(buf0, srcs, row_start, cnt, dinv, b2, buf1, N);
    // decode
    k_decode<<<(EL + 15) / 16, 256, 0, stream>>>(buf1, eli, out, EL);
}